// Round 10
// baseline (1380.597 us; speedup 1.0000x reference)
//
#include <hip/hip_runtime.h>
#include <math.h>
#include <stdint.h>

typedef _Float16 f16;
typedef _Float16 f16x8 __attribute__((ext_vector_type(8)));
typedef float    f32x16 __attribute__((ext_vector_type(16)));

#define NBLK 256
#define NTHR 1024
#define MROW 64

// ---- d_ws fragment layout (identical to r6-r9, validated) ----
#define FC1_F 512
#define FC2_F 640
#define ENC_F 656
#define TOT_F 1232
#define TOT_E (TOT_F*512)

#define MFMA32(a,b,c) __builtin_amdgcn_mfma_f32_32x32x16_f16((a),(b),(c),0,0,0)
#define VMW0()  asm volatile("s_waitcnt vmcnt(0)" ::: "memory")
#define VMW1()  asm volatile("s_waitcnt vmcnt(1)" ::: "memory")
#define VMW2()  asm volatile("s_waitcnt vmcnt(2)" ::: "memory")
#define LGKM0() asm volatile("s_waitcnt lgkmcnt(0)" ::: "memory")
#define BARR()  do { __builtin_amdgcn_s_barrier(); asm volatile("" ::: "memory"); } while(0)

__device__ __forceinline__ void gld16(const f16* g, f16* lds){
  __builtin_amdgcn_global_load_lds(
      (const __attribute__((address_space(1))) void*)(uintptr_t)(const void*)g,
      (__attribute__((address_space(3))) void*)(uint32_t)(uintptr_t)(void*)lds,
      16, 0, 0);
}

__device__ __forceinline__ float sigm(float v){
  return __fdividef(1.0f, 1.0f + __expf(-v));
}
__device__ __forceinline__ float tanh_f(float v){
  float t = fminf(v, 8.0f);
  float e = __expf(2.0f * t);
  return 1.0f - 2.0f * __fdividef(1.0f, e + 1.0f);
}
__device__ __forceinline__ int eX(int row, int k){ return row*128 + (k ^ ((row & 7) << 3)); }

// ---------------- prep: pack weights as fp16 32x32x16 B-fragments (byte-identical r6-r9) ----------------
__global__ void prep_pack(const float* __restrict__ eWih, const float* __restrict__ eWhh,
                          const float* __restrict__ dWih, const float* __restrict__ dWhh,
                          const float* __restrict__ f1W,  const float* __restrict__ f2W,
                          f16* __restrict__ ws16)
{
  int idx = blockIdx.x * 256 + threadIdx.x;
  if (idx >= TOT_E) return;
  int frag = idx >> 9;
  int lo   = idx & 511;
  int l    = lo >> 3;
  int jj   = lo & 7;
  int c32  = l & 31;
  int half = l >> 5;
  int kin  = half*8 + jj;
  float v = 0.0f;
  if (frag < FC1_F){
    int ct = frag >> 6, st = (frag >> 4) & 3, ks = frag & 15;
    int col = ct*32 + c32, k = ks*16 + kin;
    if      (st == 0) v = dWih[col*256 + k]        + dWhh[col*256 + k];
    else if (st == 1) v = dWih[(256+col)*256 + k]  + dWhh[(256+col)*256 + k];
    else if (st == 2) v = dWih[(512+col)*256 + k];
    else              v = dWhh[(512+col)*256 + k];
  } else if (frag < FC2_F){
    int f = frag - FC1_F, ct = f >> 4, ks = f & 15;
    int col = ct*32 + c32, k = ks*16 + kin;
    v = f1W[col*256 + k];
  } else if (frag < ENC_F){
    int ks = frag - FC2_F, k = ks*16 + kin;
    v = (c32 < 2) ? f2W[c32*256 + k] : 0.0f;
  } else {
    int f = frag - ENC_F, ct = f / 72, r = f % 72;
    int col = ct*32 + c32;
    if (r < 24){ int st = r >> 3, ks = r & 7;  v = eWih[(st*256 + col)*128 + ks*16 + kin]; }
    else { r -= 24; int st = r >> 4, ks = r & 15; v = eWhh[(st*256 + col)*256 + ks*16 + kin]; }
  }
  ws16[idx] = (f16)v;
}

// ---------------- fused persistent kernel: 16 waves, pair (w, w+8) shares col-tile ----------------
__global__ __launch_bounds__(NTHR, 1)
void fused_net(const float* __restrict__ x,
               const float* __restrict__ emW, const float* __restrict__ emb_,
               const float* __restrict__ evW, const float* __restrict__ evb,
               const float* __restrict__ ebih, const float* __restrict__ ebhh,
               const float* __restrict__ dbih, const float* __restrict__ dbhh,
               const float* __restrict__ f1b, const float* __restrict__ f2b,
               const f16* __restrict__ ws16, float* __restrict__ out)
{
  __shared__ __align__(16) f16 hA[16384];   // [64][256] h ping
  __shared__ __align__(16) f16 hB[16384];   // [64][256] h pong / fc1-out (xb overlays hq[0:8192])
  __shared__ __align__(16) f16 stg[49152];  // 8 ct x 3 slots x 2048 f16 (4KB slots)

  const int tid  = threadIdx.x;
  const int r0   = blockIdx.x * MROW;
  const int l    = tid & 63;
  const int w    = tid >> 6;       // 0..15
  const int ct   = w & 7;          // column tile (32 cols)
  const int rt   = w >> 3;         // row tile: 0 = rows 0-31, 1 = rows 32-63
  const int c32  = l & 31;
  const int half = l >> 5;
  const bool lw  = (w < 8);

  f16* hp = hA;
  f16* hq = hB;

  const int sw    = (l & 7) << 3;
  const int abase = (rt*32 + c32)*256 + ((half*8) ^ sw);
  const int xbase = (rt*32 + c32)*128 + ((half*8) ^ sw);
  const int colm  = ct*32 + c32;

  f16* sl0 = stg + (size_t)(ct*3 + 0)*2048;
  f16* sl1 = stg + (size_t)(ct*3 + 1)*2048;
  f16* sl2 = stg + (size_t)(ct*3 + 2)*2048;

  const f16* wdecL = ws16 + (size_t)(ct*64)*512          + (size_t)l*8;
  const f16* wfc1L = ws16 + (size_t)(FC1_F + ct*16)*512  + (size_t)l*8;
  const f16* wfc2L = ws16 + (size_t)FC2_F*512            + (size_t)l*8;
  const f16* wencL = ws16 + (size_t)(ENC_F + ct*72)*512  + (size_t)l*8;

  // split-issue helpers: lower wave stages streams 0-1, upper wave streams 2(+3)
  auto enc_issue = [&](int n, f16* slot){
    if (n < 8){
      if (lw){ gld16(wencL + (size_t)(0*8 + n)*512, slot + 0*512);
               gld16(wencL + (size_t)(1*8 + n)*512, slot + 1*512); }
      else   { gld16(wencL + (size_t)(2*8 + n)*512, slot + 2*512); }
    } else {
      int ks = n - 8;
      if (lw){ gld16(wencL + (size_t)(24 + 0*16 + ks)*512, slot + 0*512);
               gld16(wencL + (size_t)(24 + 1*16 + ks)*512, slot + 1*512); }
      else   { gld16(wencL + (size_t)(24 + 2*16 + ks)*512, slot + 2*512); }
    }
  };
  auto dec_issue = [&](int n, f16* slot){
    if (lw){ gld16(wdecL + (size_t)(0*16 + n)*512, slot + 0*512);
             gld16(wdecL + (size_t)(1*16 + n)*512, slot + 1*512); }
    else   { gld16(wdecL + (size_t)(2*16 + n)*512, slot + 2*512);
             gld16(wdecL + (size_t)(3*16 + n)*512, slot + 3*512); }
  };
  auto fc1_issue = [&](int f, f16* slot){
    if (lw){ gld16(wfc1L + (size_t)(f*4 + 0)*512, slot + 0*512);
             gld16(wfc1L + (size_t)(f*4 + 1)*512, slot + 1*512); }
    else   { gld16(wfc1L + (size_t)(f*4 + 2)*512, slot + 2*512);
             gld16(wfc1L + (size_t)(f*4 + 3)*512, slot + 3*512); }
  };

  for (int i = tid; i < 16384; i += NTHR) hA[i] = (f16)0.0f;   // h0 = 0

  // =============== ENCODER: 9 GRU steps ===============
  {
    const float ebr = ebih[colm]       + ebhh[colm];
    const float ebz = ebih[256 + colm] + ebhh[256 + colm];
    const float ebn = ebih[512 + colm];
    const float ebh = ebhh[512 + colm];

    enc_issue(0, sl0);
    enc_issue(1, sl1);

    #pragma unroll 1
    for (int t = 0; t < 9; ++t){
      f16* xb = hq;   // xb overlays hq[0:8192] (dead until epilogue overwrites it)
      { // xt = tanh(embedding) -> xb
        int e  = tid & 127;
        int rq = tid >> 7;                  // 0..7 -> rows rq*8..+7
        const float* Wp = (t < 8) ? (evW + e*6) : (emW + e*6);
        float bb = (t < 8) ? evb[e] : emb_[e];
        float w0 = Wp[0], w1 = Wp[1], w2 = Wp[2], w3 = Wp[3], w4 = Wp[4], w5 = Wp[5];
        int xo = (t < 8) ? (6 + t*6) : 0;
        #pragma unroll 1
        for (int rr = 0; rr < 8; ++rr){
          int row = rq*8 + rr;
          const float* xs = x + (size_t)(r0 + row)*54 + xo;
          float a = bb + xs[0]*w0 + xs[1]*w1 + xs[2]*w2 + xs[3]*w3 + xs[4]*w4 + xs[5]*w5;
          xb[eX(row, e)] = (f16)tanh_f(a);
        }
      }
      LGKM0(); BARR();   // xb visible (t=0: also hA memset)

      f32x16 aR = 0.f, aZ = 0.f, aN = 0.f, aH = 0.f;
      #pragma unroll 1
      for (int n = 0; n < 24; ++n){
        if (n < 23){ if (lw) VMW2(); else VMW1(); } else { VMW0(); }
        BARR();
        if (n < 22) enc_issue(n + 2, sl2);
        f16x8 b0 = *(const f16x8*)(sl0 + 0*512 + l*8);
        f16x8 b1 = *(const f16x8*)(sl0 + 1*512 + l*8);
        f16x8 b2 = *(const f16x8*)(sl0 + 2*512 + l*8);
        if (n < 8){
          f16x8 a0 = *(const f16x8*)(xb + (xbase ^ (n << 4)));
          aR = MFMA32(a0, b0, aR);  aZ = MFMA32(a0, b1, aZ);  aN = MFMA32(a0, b2, aN);
        } else {
          f16x8 a0 = *(const f16x8*)(hp + (abase ^ ((n - 8) << 4)));
          aR = MFMA32(a0, b0, aR);  aZ = MFMA32(a0, b1, aZ);  aH = MFMA32(a0, b2, aH);
        }
        f16* tt = sl0; sl0 = sl1; sl1 = sl2; sl2 = tt;
      }
      // epilogue -> hq (my rt rows)
      #pragma unroll
      for (int rg = 0; rg < 16; ++rg){
        int rr  = (rg & 3) + 8*(rg >> 2) + 4*half;
        int row = rt*32 + rr;
        int el  = row*256 + (colm ^ ((rr & 7) << 3));
        float rv = sigm(aR[rg] + ebr);
        float zv = sigm(aZ[rg] + ebz);
        float nv = tanh_f(aN[rg] + ebn + rv*(aH[rg] + ebh));
        float ho = (float)hp[el];
        hq[el] = (f16)(nv + zv*(ho - nv));
      }
      LGKM0(); BARR();
      { f16* tmp = hp; hp = hq; hq = tmp; }
      if (t < 8){ enc_issue(0, sl0); enc_issue(1, sl1); }
    }
  }

  // =============== DECODER: 32 x (GRU + fc1 + fc2) ===============
  const float dbr = dbih[colm]       + dbhh[colm];
  const float dbz = dbih[256 + colm] + dbhh[256 + colm];
  const float dbn = dbih[512 + colm];
  const float dbh = dbhh[512 + colm];
  const float f1bb = f1b[colm];
  const float f2bb = (c32 < 2) ? f2b[c32] : 0.0f;

  dec_issue(0, sl0);
  dec_issue(1, sl1);

  #pragma unroll 1
  for (int s = 0; s < 32; ++s){
    // ---- GRU: reads hp, writes h_new -> hq ----
    {
      f32x16 aR = 0.f, aZ = 0.f, aN = 0.f, aH = 0.f;
      #pragma unroll 1
      for (int u = 0; u < 16; ++u){
        VMW2();
        BARR();
        int n2 = u + 2;
        if (n2 < 16) dec_issue(n2, sl2); else fc1_issue(n2 - 16, sl2);
        f16x8 b0 = *(const f16x8*)(sl0 + 0*512 + l*8);
        f16x8 b1 = *(const f16x8*)(sl0 + 1*512 + l*8);
        f16x8 b2 = *(const f16x8*)(sl0 + 2*512 + l*8);
        f16x8 b3 = *(const f16x8*)(sl0 + 3*512 + l*8);
        f16x8 a0 = *(const f16x8*)(hp + (abase ^ (u << 4)));
        aR = MFMA32(a0, b0, aR);  aZ = MFMA32(a0, b1, aZ);
        aN = MFMA32(a0, b2, aN);  aH = MFMA32(a0, b3, aH);
        f16* tt = sl0; sl0 = sl1; sl1 = sl2; sl2 = tt;
      }
      #pragma unroll
      for (int rg = 0; rg < 16; ++rg){
        int rr  = (rg & 3) + 8*(rg >> 2) + 4*half;
        int row = rt*32 + rr;
        int el  = row*256 + (colm ^ ((rr & 7) << 3));
        float rv = sigm(aR[rg] + dbr);
        float zv = sigm(aZ[rg] + dbz);
        float nv = tanh_f(aN[rg] + dbn + rv*(aH[rg] + dbh));
        float ho = (float)hp[el];
        hq[el] = (f16)(nv + zv*(ho - nv));
      }
    }
    LGKM0(); BARR();

    // ---- FC1: relu(h_new @ W1.T + b1): reads hq, writes -> hp (h_old dead) ----
    {
      f32x16 aF = 0.f;
      #pragma unroll 1
      for (int f = 0; f < 4; ++f){
        VMW2();
        BARR();
        if (f < 2) fc1_issue(f + 2, sl2);
        else       dec_issue(f - 2, sl2);   // next step's GRU batches 0,1 (always: keeps vmcnt sound)
        f16x8 c0 = *(const f16x8*)(sl0 + 0*512 + l*8);
        f16x8 c1 = *(const f16x8*)(sl0 + 1*512 + l*8);
        f16x8 c2 = *(const f16x8*)(sl0 + 2*512 + l*8);
        f16x8 c3 = *(const f16x8*)(sl0 + 3*512 + l*8);
        int kb = f*4;
        f16x8 a0 = *(const f16x8*)(hq + (abase ^ ((kb + 0) << 4)));
        aF = MFMA32(a0, c0, aF);
        f16x8 a1 = *(const f16x8*)(hq + (abase ^ ((kb + 1) << 4)));
        aF = MFMA32(a1, c1, aF);
        f16x8 a2 = *(const f16x8*)(hq + (abase ^ ((kb + 2) << 4)));
        aF = MFMA32(a2, c2, aF);
        f16x8 a3 = *(const f16x8*)(hq + (abase ^ ((kb + 3) << 4)));
        aF = MFMA32(a3, c3, aF);
        f16* tt = sl0; sl0 = sl1; sl1 = sl2; sl2 = tt;
      }
      #pragma unroll
      for (int rg = 0; rg < 16; ++rg){
        int rr  = (rg & 3) + 8*(rg >> 2) + 4*half;
        int row = rt*32 + rr;
        int el  = row*256 + (colm ^ ((rr & 7) << 3));
        hp[el] = (f16)fmaxf(aF[rg] + f1bb, 0.0f);
      }
    }
    LGKM0(); BARR();

    // ---- FC2 (ct==0 pair: wave 0 rows 0-31, wave 8 rows 32-63), B direct global->reg ----
    if (ct == 0){
      f32x16 a2 = 0.f;
      #pragma unroll 1
      for (int ks = 0; ks < 16; ++ks){
        f16x8 bv = *(const f16x8*)(wfc2L + (size_t)ks*512);
        f16x8 a0 = *(const f16x8*)(hp + (abase ^ (ks << 4)));
        a2 = MFMA32(a0, bv, a2);
      }
      if (c32 < 2){
        #pragma unroll
        for (int rg = 0; rg < 16; ++rg){
          int rr  = (rg & 3) + 8*(rg >> 2) + 4*half;
          int row = rt*32 + rr;
          out[((size_t)(r0 + row)*32 + s)*2 + c32] = tanh_f(a2[rg] + f2bb);
        }
      }
    }
    // no extra barrier: next GRU's per-unit barrier + VMW synchronizes; FC2 reads hp,
    // which is only rewritten after next GRU's 16 barriers.
    { f16* tmp = hp; hp = hq; hq = tmp; }
  }
}

extern "C" void kernel_launch(void* const* d_in, const int* in_sizes, int n_in,
                              void* d_out, int out_size, void* d_ws, size_t ws_size,
                              hipStream_t stream)
{
  (void)in_sizes; (void)n_in; (void)out_size; (void)ws_size;
  const float* x    = (const float*)d_in[0];
  const float* emW  = (const float*)d_in[1];
  const float* emb_ = (const float*)d_in[2];
  const float* evW  = (const float*)d_in[3];
  const float* evb  = (const float*)d_in[4];
  const float* eWih = (const float*)d_in[5];
  const float* eWhh = (const float*)d_in[6];
  const float* ebih = (const float*)d_in[7];
  const float* ebhh = (const float*)d_in[8];
  const float* dWih = (const float*)d_in[9];
  const float* dWhh = (const float*)d_in[10];
  const float* dbih = (const float*)d_in[11];
  const float* dbhh = (const float*)d_in[12];
  const float* f1W  = (const float*)d_in[13];
  const float* f1b  = (const float*)d_in[14];
  const float* f2W  = (const float*)d_in[15];
  const float* f2b  = (const float*)d_in[16];
  float* out = (float*)d_out;
  f16* ws16 = (f16*)d_ws;

  prep_pack<<<(TOT_E + 255)/256, 256, 0, stream>>>(eWih, eWhh, dWih, dWhh, f1W, f2W, ws16);
  fused_net<<<NBLK, NTHR, 0, stream>>>(x, emW, emb_, evW, evb, ebih, ebhh,
                                       dbih, dbhh, f1b, f2b, ws16, out);
}